// Round 9
// baseline (1069.156 us; speedup 1.0000x reference)
//
#include <hip/hip_runtime.h>
#include <math.h>

// ---------------------------------------------------------------------------
// CapsuleNet forward (round 9): prim GEMM rebuilt m97-style.
//  - 16x16x32 MFMA, wave tile 64x64 (4x4 frags: 16 MFMA / 8 ds_read_b128)
//  - BM=128 BN=256 (single n-tile), 512 threads (8 waves, 2m x 4n)
//  - global_load_lds width=16 staging, LDK=32 + XOR seg swizzle (no padding)
//  - split-K x8, kt = bx&7 -> XCD-pinned B slice; atomic accumulate
// Everything else unchanged from round 8.
// ---------------------------------------------------------------------------

typedef _Float16 h16;
typedef h16 frag8 __attribute__((ext_vector_type(8)));    // 8 halves = 16 B
typedef float f32x4 __attribute__((ext_vector_type(4)));

#define AS1 __attribute__((address_space(1)))
#define AS3 __attribute__((address_space(3)))

// workspace layout (BYTE offsets).
#define OFFB_HHI   0L             // 52428800 halves = 104857600 B
#define OFFB_WTHI  209715200L     // 5308416 halves = 10616832 B
#define OFFB_WT1   230948864L     // 20736 floats = 82944 B
#define OFFB_C     231031808L     // 4718592 floats -> end 249906176
#define WS_BYTES   249906176L
// aliased into dead h region after prim_gemm:
#define OFFB_PRI   0L             // 94371840 halves = 188743680 B (priors fp16)
#define OFFB_UT    188743680L     // 4718592 floats -> 207618048 OK
// aliased into dead wt region after prim_gemm:
#define OFFB_V     209715200L     // 81920 floats
#define OFFB_MSK   210042880L     // 81920 floats
#define OFFB_D1    210370560L     // 262144 floats
#define OFFB_D2    211419136L     // 524288 floats -> 213516288 OK

// --------------------------------------------------------------------------
__global__ void transpose_w1(const float* __restrict__ w, float* __restrict__ wt) {
    int i = blockIdx.x * 256 + threadIdx.x;          // 20736 exact
    int k = i >> 8, oc = i & 255;
    wt[i] = w[oc * 81 + k];
}

// prim weights -> B^T fp16: wt[oc][k], k = tap*256+ic. LDS transpose.
__global__ __launch_bounds__(256) void split_pw(const float* __restrict__ w,
                                                h16* __restrict__ whi) {
    __shared__ float s[2592];                        // 32 ic x 81 taps
    int oc = blockIdx.x;
    int tid = threadIdx.x;
    long src0 = (long)oc * 20736;
    long dst0 = (long)oc * 20736;
    for (int ch = 0; ch < 8; ++ch) {
        int ic0 = ch * 32;
        __syncthreads();
        for (int e = tid; e < 2592; e += 256) s[e] = w[src0 + ic0 * 81 + e];
        __syncthreads();
        for (int e = tid; e < 2592; e += 256) {
            int tap = e >> 5, icf = e & 31;
            whi[dst0 + tap * 256 + ic0 + icf] = (h16)s[icf * 81 + tap];
        }
    }
}

// C pre-fill with bias (split-K zero-init)
__global__ void init_C(const float* __restrict__ bias, float* __restrict__ C) {
    int i = blockIdx.x * 256 + threadIdx.x;          // 4718592 exact
    C[i] = bias[i & 255];
}

// --------------------------------------------------------------------------
// conv1: x[b][28][28] * w -> h fp16, NHWC [b][y][x][oc], ReLU.
__global__ __launch_bounds__(448) void conv1_k(const float* __restrict__ x,
                                               const float* __restrict__ wt1,
                                               const float* __restrict__ bias,
                                               h16* __restrict__ hhi) {
    __shared__ float xs[784];
    int b = blockIdx.x;
    int tid = threadIdx.x;
    for (int i = tid; i < 784; i += 448) xs[i] = x[b * 784 + i];
    __syncthreads();
    if (tid >= 400) return;
    int oy = tid / 20, ox = tid - oy * 20;
    int xbase = oy * 28 + ox;
    float xv[81];
#pragma unroll
    for (int ky = 0; ky < 9; ++ky)
#pragma unroll
        for (int kx = 0; kx < 9; ++kx)
            xv[ky * 9 + kx] = xs[xbase + ky * 28 + kx];
    long hb = ((long)(b * 20 + oy) * 20 + ox) * 256;
    for (int ocg = 0; ocg < 16; ++ocg) {
        int oc0 = ocg * 16;
        float acc[16];
#pragma unroll
        for (int j = 0; j < 16; ++j) acc[j] = bias[oc0 + j];
#pragma unroll
        for (int t = 0; t < 81; ++t) {
            const float* wr = wt1 + t * 256 + oc0;   // wave-uniform -> s_load
            float xt = xv[t];
#pragma unroll
            for (int j = 0; j < 16; ++j) acc[j] = fmaf(wr[j], xt, acc[j]);
        }
        frag8 h0, h1;
#pragma unroll
        for (int j = 0; j < 8; ++j) {
            h0[j] = (h16)fmaxf(acc[j], 0.f);
            h1[j] = (h16)fmaxf(acc[j + 8], 0.f);
        }
        *(frag8*)(hhi + hb + oc0)     = h0;
        *(frag8*)(hhi + hb + oc0 + 8) = h1;
    }
}

// --------------------------------------------------------------------------
// prim conv MFMA GEMM, m97-style.
// BM=128 BN=256 BK=32 halves; grid 1152: kt = bx&7, mt = bx>>3.
// LDS: A 128x32h (8 KB) + B 256x32h (16 KB), LDK=32, XOR seg swizzle:
//   slot (row, p) holds global 8-half segment  p ^ (row&3).
// Staged by global_load_lds width=16: thread t -> row t>>2, slot t&3.
__global__ __launch_bounds__(512, 4) void prim_gemm_mfma(
        const h16* __restrict__ Ahi, const h16* __restrict__ Bhi,
        float* __restrict__ C) {
    __shared__ h16 As[128 * 32];
    __shared__ h16 Bs[256 * 32];
    int tid = threadIdx.x;
    int bx = blockIdx.x;                  // 1152 blocks
    int kt = bx & 7;
    int mt = bx >> 3;                     // 0..143
    int kb0 = kt * 81;

    // ---- staging geometry ----
    int ra = tid >> 2;                    // row 0..127
    int p  = tid & 3;                     // slot
    int sseg = p ^ (ra & 3);              // global segment stored in this slot
    int ma = mt * 128 + ra;
    int b = ma / 36, pos = ma - b * 36;
    int oy = pos / 6, ox = pos - oy * 6;
    long abase = ((long)(b * 20 + 2 * oy) * 20 + 2 * ox) * 256 + sseg * 8;
    long bbase = (long)ra * 20736 + sseg * 8;      // oc = ra (+128 for inst 2)
    int wave = tid >> 6;
    h16* ldsA  = As + wave * 512;                  // wave-uniform DMA bases
    h16* ldsB0 = Bs + wave * 512;
    h16* ldsB1 = Bs + 4096 + wave * 512;

    // ---- fragment geometry (lane-constant LDS offsets) ----
    int wm = wave >> 2, wn = wave & 3;    // wave tile (wm*64, wn*64)
    int lane = tid & 63;
    int lm = lane & 15, quad = lane >> 4;
    int pf = quad ^ (lm & 3);             // swizzled slot for this lane's frags
    const h16* afp[4];
    const h16* bfp[4];
#pragma unroll
    for (int mi = 0; mi < 4; ++mi)
        afp[mi] = As + (wm * 64 + mi * 16 + lm) * 32 + pf * 8;
#pragma unroll
    for (int ni = 0; ni < 4; ++ni)
        bfp[ni] = Bs + (wn * 64 + ni * 16 + lm) * 32 + pf * 8;

    f32x4 acc[4][4];
#pragma unroll
    for (int i = 0; i < 4; ++i)
#pragma unroll
        for (int j = 0; j < 4; ++j) acc[i][j] = (f32x4){0.f, 0.f, 0.f, 0.f};

    for (int it = 0; it < 81; ++it) {
        int kb = kb0 + it;
        int tap = kb >> 3;
        int ic0 = (kb & 7) << 5;
        int ky = tap / 9, kx = tap - ky * 9;
        long aoff = abase + (ky * 20 + kx) * 256 + ic0;
        long boff = bbase + (long)kb * 32;
        __syncthreads();                  // prev iter's ds_reads done
        __builtin_amdgcn_global_load_lds(
            (const AS1 void*)(Ahi + aoff), (AS3 void*)ldsA, 16, 0, 0);
        __builtin_amdgcn_global_load_lds(
            (const AS1 void*)(Bhi + boff), (AS3 void*)ldsB0, 16, 0, 0);
        __builtin_amdgcn_global_load_lds(
            (const AS1 void*)(Bhi + boff + 128L * 20736), (AS3 void*)ldsB1, 16, 0, 0);
        __syncthreads();                  // compiler drains vmcnt before this

        frag8 af[4], bf[4];
#pragma unroll
        for (int mi = 0; mi < 4; ++mi) af[mi] = *(const frag8*)afp[mi];
#pragma unroll
        for (int ni = 0; ni < 4; ++ni) bf[ni] = *(const frag8*)bfp[ni];
#pragma unroll
        for (int mi = 0; mi < 4; ++mi)
#pragma unroll
            for (int ni = 0; ni < 4; ++ni)
                acc[mi][ni] = __builtin_amdgcn_mfma_f32_16x16x32_f16(
                    af[mi], bf[ni], acc[mi][ni], 0, 0, 0);
    }

    // epilogue: C/D col = lane&15, row = quad*4 + reg; atomic split-K
#pragma unroll
    for (int ni = 0; ni < 4; ++ni) {
        int n = wn * 64 + ni * 16 + lm;
#pragma unroll
        for (int mi = 0; mi < 4; ++mi) {
            int m = mt * 128 + wm * 64 + mi * 16 + quad * 4;
#pragma unroll
            for (int r = 0; r < 4; ++r)
                atomicAdd(&C[(long)(m + r) * 256 + n], acc[mi][ni][r]);
        }
    }
}

// --------------------------------------------------------------------------
// squash: C[(b*36+pos)][256] -> ut[n][b][8], n = ci*36+pos.
__global__ void squash_k(const float* __restrict__ C, float* __restrict__ ut) {
    int t = blockIdx.x * 256 + threadIdx.x;          // 589824 exact
    int row = t >> 5;                                 // (b*36+pos)
    int ci = t & 31;
    int b = row / 36, pos = row - b * 36;
    const float* src = C + (long)row * 256 + ci;
    float v[8]; float sn = 0.f;
#pragma unroll
    for (int i = 0; i < 8; ++i) { v[i] = src[i * 32]; sn = fmaf(v[i], v[i], sn); }
    float scale = (sn / (1.f + sn)) / sqrtf(sn);
    float* dst = ut + ((long)(ci * 36 + pos) * 512 + b) * 8;
    float4 o0 = make_float4(v[0]*scale, v[1]*scale, v[2]*scale, v[3]*scale);
    float4 o1 = make_float4(v[4]*scale, v[5]*scale, v[6]*scale, v[7]*scale);
    *(float4*)(dst) = o0;
    *(float4*)(dst + 4) = o1;
}

// --------------------------------------------------------------------------
// Phase A: priors[c,b,n,:16] = ut[n,b,:8] @ rw[c,n,:8,:16], fp16 out.
__global__ __launch_bounds__(256) void priors_k(const float* __restrict__ ut,
                                                const float* __restrict__ rw,
                                                h16* __restrict__ priors) {
    int bid = blockIdx.x;                 // 1440 = 10 c * 144 n-groups
    int c = bid / 144, ng = bid - c * 144;
    int n0 = ng * 8;
    __shared__ float w[8][132];
    int tid = threadIdx.x;
    for (int e = tid; e < 1024; e += 256)
        w[e >> 7][e & 127] = rw[((long)c * 1152 + n0 + (e >> 7)) * 128 + (e & 127)];
    __syncthreads();
    int nl = tid & 7, bl = tid >> 3;      // bl 0..31
    int n = n0 + nl;
    for (int ch = 0; ch < 16; ++ch) {
        int b = ch * 32 + bl;
        const float4* up = (const float4*)(ut + ((long)n * 512 + b) * 8);
        float4 ua = up[0], ub = up[1];
        float uu[8] = {ua.x, ua.y, ua.z, ua.w, ub.x, ub.y, ub.z, ub.w};
        float o[16];
#pragma unroll
        for (int j = 0; j < 16; ++j) o[j] = 0.f;
#pragma unroll
        for (int i = 0; i < 8; ++i)
#pragma unroll
            for (int j = 0; j < 16; ++j)
                o[j] = fmaf(uu[i], w[nl][i * 16 + j], o[j]);
        frag8 p0, p1;
#pragma unroll
        for (int j = 0; j < 8; ++j) { p0[j] = (h16)o[j]; p1[j] = (h16)o[j + 8]; }
        h16* dst = priors + ((long)(c * 512 + b) * 1152 + n) * 16;
        *(frag8*)dst = p0;
        *(frag8*)(dst + 8) = p1;
    }
}

// --------------------------------------------------------------------------
// Phase B: 3-iter routing from materialized fp16 priors. Block per (c,b).
__global__ __launch_bounds__(384) void routing2_k(const h16* __restrict__ priors,
                                                  float* __restrict__ vbuf) {
    int c = blockIdx.x >> 9;
    int b = blockIdx.x & 511;
    int tid = threadIdx.x;
    int wid = tid >> 6;
    int lane = tid & 63;
    __shared__ float wred[6][20];

    float pr[3][16];
#pragma unroll
    for (int r = 0; r < 3; ++r) {
        int n = tid + r * 384;
        const h16* pp = priors + ((long)(c * 512 + b) * 1152 + n) * 16;
        frag8 p0 = *(const frag8*)pp;
        frag8 p1 = *(const frag8*)(pp + 8);
#pragma unroll
        for (int o = 0; o < 8; ++o) { pr[r][o] = (float)p0[o]; pr[r][o + 8] = (float)p1[o]; }
    }

    float l0 = 0.f, l1 = 0.f, l2 = 0.f;
    float vout[16];
    for (int it = 0; it < 3; ++it) {
        float lm = fmaxf(fmaxf(l0, l1), l2);
#pragma unroll
        for (int m = 32; m >= 1; m >>= 1) lm = fmaxf(lm, __shfl_xor(lm, m));
        if (lane == 0) wred[wid][17] = lm;
        __syncthreads();
        float maxv = wred[0][17];
#pragma unroll
        for (int w = 1; w < 6; ++w) maxv = fmaxf(maxv, wred[w][17]);

        float e0 = expf(l0 - maxv), e1 = expf(l1 - maxv), e2 = expf(l2 - maxv);
        float red[17];
#pragma unroll
        for (int o = 0; o < 16; ++o)
            red[o] = fmaf(e0, pr[0][o], fmaf(e1, pr[1][o], e2 * pr[2][o]));
        red[16] = e0 + e1 + e2;
#pragma unroll
        for (int o = 0; o < 17; ++o) {
#pragma unroll
            for (int m = 32; m >= 1; m >>= 1) red[o] += __shfl_xor(red[o], m);
        }
        __syncthreads();
        if (lane == 0) {
#pragma unroll
            for (int o = 0; o < 17; ++o) wred[wid][o] = red[o];
        }
        __syncthreads();
        float sv[17];
#pragma unroll
        for (int o = 0; o < 17; ++o) {
            float tacc = wred[0][o];
#pragma unroll
            for (int w = 1; w < 6; ++w) tacc += wred[w][o];
            sv[o] = tacc;
        }
        float inv = 1.f / sv[16];
        float sn = 0.f;
#pragma unroll
        for (int o = 0; o < 16; ++o) { float s = sv[o] * inv; sn = fmaf(s, s, sn); }
        float scale = (sn / (1.f + sn)) / sqrtf(sn);
#pragma unroll
        for (int o = 0; o < 16; ++o) vout[o] = sv[o] * inv * scale;

        if (it < 2) {
            float d0 = 0.f, d1 = 0.f, d2 = 0.f;
#pragma unroll
            for (int o = 0; o < 16; ++o) {
                d0 = fmaf(pr[0][o], vout[o], d0);
                d1 = fmaf(pr[1][o], vout[o], d1);
                d2 = fmaf(pr[2][o], vout[o], d2);
            }
            l0 += d0; l1 += d1; l2 += d2;
        }
    }
    if (tid < 16) vbuf[(b * 10 + c) * 16 + tid] = vout[tid];
}

// --------------------------------------------------------------------------
__global__ void mask_k(const float* __restrict__ vbuf, float* __restrict__ out,
                       float* __restrict__ masked) {
    int b = blockIdx.x * 256 + threadIdx.x;
    if (b >= 512) return;
    const float* vp = vbuf + b * 160;
    float cls[10]; int best = 0; float bv = -1.f;
#pragma unroll
    for (int cc = 0; cc < 10; ++cc) {
        float sn = 0.f;
#pragma unroll
        for (int o = 0; o < 16; ++o) { float v = vp[cc * 16 + o]; sn = fmaf(v, v, sn); }
        cls[cc] = sqrtf(sn);
        if (cls[cc] > bv) { bv = cls[cc]; best = cc; }
    }
#pragma unroll
    for (int cc = 0; cc < 10; ++cc) {
        out[b * 10 + cc] = (cc == best) ? 1.f : 0.f;
        out[406528 + b * 10 + cc] = cls[cc];
    }
#pragma unroll
    for (int cc = 0; cc < 10; ++cc) {
        float keep = (cc == best) ? 1.f : 0.f;
#pragma unroll
        for (int o = 0; o < 16; ++o)
            masked[b * 160 + cc * 16 + o] = keep * vp[cc * 16 + o];
    }
}

// --------------------------------------------------------------------------
template <int ACT>
__global__ __launch_bounds__(256) void dec_gemm(const float* __restrict__ A,
                                                const float* __restrict__ Bw,
                                                const float* __restrict__ bias,
                                                float* __restrict__ C,
                                                int M, int N, int K) {
    __shared__ float As[16][68];
    __shared__ float Bs[16][68];
    int ntiles = (N + 63) >> 6;
    int mt = blockIdx.x / ntiles, nt = blockIdx.x - mt * ntiles;
    int m0 = mt * 64, n0 = nt * 64;
    int tid = threadIdx.x;
    int tx = tid & 15, ty = tid >> 4;
    int am = tid >> 2, ak = (tid & 3) * 4;
    int bk = tid >> 4, bn = (tid & 15) * 4;
    float acc[4][4];
#pragma unroll
    for (int i = 0; i < 4; ++i)
#pragma unroll
        for (int j = 0; j < 4; ++j) acc[i][j] = 0.f;

    for (int k0 = 0; k0 < K; k0 += 16) {
        float4 av = *(const float4*)(A + (m0 + am) * K + k0 + ak);
        float4 bv = make_float4(0.f, 0.f, 0.f, 0.f);
        if (n0 + bn < N) bv = *(const float4*)(Bw + (k0 + bk) * N + n0 + bn);
        __syncthreads();
        As[ak + 0][am] = av.x;
        As[ak + 1][am] = av.y;
        As[ak + 2][am] = av.z;
        As[ak + 3][am] = av.w;
        *(float4*)&Bs[bk][bn] = bv;
        __syncthreads();
#pragma unroll
        for (int kk = 0; kk < 16; ++kk) {
            float4 a = *(const float4*)&As[kk][ty * 4];
            float4 bb = *(const float4*)&Bs[kk][tx * 4];
            float aa[4] = {a.x, a.y, a.z, a.w};
            float bbb[4] = {bb.x, bb.y, bb.z, bb.w};
#pragma unroll
            for (int i = 0; i < 4; ++i)
#pragma unroll
                for (int j = 0; j < 4; ++j)
                    acc[i][j] = fmaf(aa[i], bbb[j], acc[i][j]);
        }
    }
#pragma unroll
    for (int i = 0; i < 4; ++i) {
        int m = m0 + ty * 4 + i;
#pragma unroll
        for (int j = 0; j < 4; ++j) {
            int n = n0 + tx * 4 + j;
            if (n < N) {
                float v = acc[i][j] + bias[n];
                if (ACT == 0) v = fmaxf(v, 0.f);
                else          v = 1.f / (1.f + expf(-v));
                C[m * N + n] = v;
            }
        }
    }
}

// --------------------------------------------------------------------------
extern "C" void kernel_launch(void* const* d_in, const int* in_sizes, int n_in,
                              void* d_out, int out_size, void* d_ws, size_t ws_size,
                              hipStream_t stream) {
    const float* x   = (const float*)d_in[0];
    const float* w1  = (const float*)d_in[1];
    const float* b1  = (const float*)d_in[2];
    const float* pw  = (const float*)d_in[3];
    const float* pb  = (const float*)d_in[4];
    const float* rw  = (const float*)d_in[5];
    const float* dw1 = (const float*)d_in[6];
    const float* db1 = (const float*)d_in[7];
    const float* dw2 = (const float*)d_in[8];
    const float* db2 = (const float*)d_in[9];
    const float* dw3 = (const float*)d_in[10];
    const float* db3 = (const float*)d_in[11];
    float* out = (float*)d_out;
    char* wsb  = (char*)d_ws;
    if (ws_size < (size_t)WS_BYTES) return;

    h16*   hhi  = (h16*)(wsb + OFFB_HHI);
    h16*   wthi = (h16*)(wsb + OFFB_WTHI);
    float* wt1  = (float*)(wsb + OFFB_WT1);
    float* Cbuf = (float*)(wsb + OFFB_C);
    h16*   pri  = (h16*)(wsb + OFFB_PRI);
    float* ut   = (float*)(wsb + OFFB_UT);
    float* vbuf = (float*)(wsb + OFFB_V);
    float* msk  = (float*)(wsb + OFFB_MSK);
    float* d1   = (float*)(wsb + OFFB_D1);
    float* d2   = (float*)(wsb + OFFB_D2);

    transpose_w1<<<81, 256, 0, stream>>>(w1, wt1);
    split_pw<<<256, 256, 0, stream>>>(pw, wthi);
    conv1_k<<<512, 448, 0, stream>>>(x, wt1, b1, hhi);
    init_C<<<18432, 256, 0, stream>>>(pb, Cbuf);
    prim_gemm_mfma<<<1152, 512, 0, stream>>>(hhi, wthi, Cbuf);
    squash_k<<<2304, 256, 0, stream>>>(Cbuf, ut);      // h region dead now
    priors_k<<<1440, 256, 0, stream>>>(ut, rw, pri);
    routing2_k<<<5120, 384, 0, stream>>>(pri, vbuf);
    mask_k<<<2, 256, 0, stream>>>(vbuf, out, msk);
    dec_gemm<0><<<64, 256, 0, stream>>>(msk, dw1, db1, d1, 512, 512, 160);
    dec_gemm<0><<<128, 256, 0, stream>>>(d1, dw2, db2, d2, 512, 1024, 512);
    dec_gemm<1><<<104, 256, 0, stream>>>(d2, dw3, db3, out + 5120, 512, 784, 1024);
}